// Round 2
// baseline (9.838 us; speedup 1.0000x reference)
//
#include <hip/hip_runtime.h>
#include <hip/hip_bf16.h>

#define CARD 50
#define NPAIRS (2 * CARD)   // 100 output distances
#define D 64                // feature dim

// 16 lanes per pair, float4 per lane (16 lanes x 4 floats = 64 dims).
// One 64-lane wave handles 4 pairs; 25 blocks x 64 threads cover all 100.
__global__ void rips_pairs_kernel(const float* __restrict__ X,
                                  const int* __restrict__ ids,
                                  float* __restrict__ out) {
    const int lane = threadIdx.x;        // 0..63
    const int grp  = lane >> 4;          // 0..3  (pair within wave)
    const int sub  = lane & 15;          // 0..15 (16-lane group position)
    const int pair = blockIdx.x * 4 + grp;   // 0..99 exactly (25*4 = 100)

    const int i = ids[2 * pair];
    const int j = ids[2 * pair + 1];

    const float4 a = *reinterpret_cast<const float4*>(X + (size_t)i * D + sub * 4);
    const float4 b = *reinterpret_cast<const float4*>(X + (size_t)j * D + sub * 4);

    float sqi = a.x*a.x + a.y*a.y + a.z*a.z + a.w*a.w;
    float sqj = b.x*b.x + b.y*b.y + b.z*b.z + b.w*b.w;
    float dot = a.x*b.x + a.y*b.y + a.z*b.z + a.w*b.w;

    // 4-step butterfly within each 16-lane group (xor masks < 16 stay in-group)
    #pragma unroll
    for (int off = 8; off > 0; off >>= 1) {
        sqi += __shfl_xor(sqi, off, 64);
        sqj += __shfl_xor(sqj, off, 64);
        dot += __shfl_xor(dot, off, 64);
    }

    if (sub == 0) {
        // Reference semantics: d2 = max(.,0); pos = d2 > 0; d = pos ? sqrt : 0
        float d2 = fmaxf(sqi + sqj - 2.0f * dot, 0.0f);
        out[pair] = (d2 > 0.0f) ? sqrtf(d2) : 0.0f;
    }
}

extern "C" void kernel_launch(void* const* d_in, const int* in_sizes, int n_in,
                              void* d_out, int out_size, void* d_ws, size_t ws_size,
                              hipStream_t stream) {
    const float* X   = (const float*)d_in[0];   // [8192, 64] fp32
    const int*   ids = (const int*)d_in[1];     // [4*CARD] int32
    float* out = (float*)d_out;                 // [CARD, 2] fp32 = 100 floats

    rips_pairs_kernel<<<NPAIRS / 4, 64, 0, stream>>>(X, ids, out);
}